// Round 1
// baseline (1006.271 us; speedup 1.0000x reference)
//
#include <hip/hip_runtime.h>
#include <hip/hip_bf16.h>

using bf16 = __hip_bfloat16;
typedef short bf16x8 __attribute__((ext_vector_type(8)));
typedef float f32x4  __attribute__((ext_vector_type(4)));

__device__ __forceinline__ float leakyf(float x) { return x >= 0.f ? x : 0.01f * x; }

typedef const __attribute__((address_space(1))) unsigned int* gptr_t;
typedef __attribute__((address_space(3))) unsigned int* lptr_t;
__device__ __forceinline__ void gload_lds16(const void* g, void* l) {
  __builtin_amdgcn_global_load_lds((gptr_t)g, (lptr_t)l, 16, 0, 0);
}

// ---------------------------------------------------------------------------
// Weight convert/transpose: fp32 [K,Nc] -> bf16 [Nc,K] (B-operand wants n-major)
// jobs: type 0 pu_W1 [320,640]->[640,320]; 1 pu_W2 [640,320]->[320,640];
//       2 gu_W1; 3 gu_W2; 4 c_W [640,320] -> cTh [320,320] + cTg [320,320]
// ---------------------------------------------------------------------------
__global__ void conv_w(const float* __restrict__ pu1, const float* __restrict__ pu2,
                       const float* __restrict__ gu1, const float* __restrict__ gu2,
                       const float* __restrict__ cw,
                       bf16* __restrict__ tPu1, bf16* __restrict__ tPu2,
                       bf16* __restrict__ tGu1, bf16* __restrict__ tGu2,
                       bf16* __restrict__ tCh,  bf16* __restrict__ tCg) {
  const int D = 320, H = 640;
  int job = blockIdx.y;
  int layer = job % 3, type = job / 3;
  int idx = blockIdx.x * 256 + threadIdx.x;
  if (type == 0 || type == 2) {            // [D,H] -> [H,D]
    if (idx >= D * H) return;
    const float* s = (type == 0 ? pu1 : gu1) + (size_t)layer * D * H;
    bf16* d = (type == 0 ? tPu1 : tGu1) + (size_t)layer * D * H;
    int r = idx / D, c = idx % D;          // d[r][c] = s[c][r]
    d[idx] = __float2bfloat16(s[(size_t)c * H + r]);
  } else if (type == 1 || type == 3) {     // [H,D] -> [D,H]
    if (idx >= D * H) return;
    const float* s = (type == 1 ? pu2 : gu2) + (size_t)layer * D * H;
    bf16* d = (type == 1 ? tPu2 : tGu2) + (size_t)layer * D * H;
    int r = idx / H, c = idx % H;          // d[r][c] = s[c][r]
    d[idx] = __float2bfloat16(s[(size_t)c * D + r]);
  } else {                                  // c_W [2D,D] -> two [D,D] transposed
    if (idx >= D * D) return;
    const float* s = cw + (size_t)layer * 2 * D * D;
    int r = idx / D, c = idx % D;          // dst[r(n)][c(k)] = s[c][r] / s[D+c][r]
    tCh[(size_t)layer * D * D + idx] = __float2bfloat16(s[(size_t)c * D + r]);
    tCg[(size_t)layer * D * D + idx] = __float2bfloat16(s[(size_t)(D + c) * D + r]);
  }
}

// ---------------------------------------------------------------------------
// Embedding gather: out[n, k*64+e] = embed[words[n,k], e]  (bf16)
// ---------------------------------------------------------------------------
__global__ void embed_k(const int* __restrict__ words, const float* __restrict__ emb,
                        bf16* __restrict__ out, int N) {
  int i = blockIdx.x * 256 + threadIdx.x;
  if (i >= N * 64) return;
  int n = i >> 6, e = i & 63;
  const int* wr = words + (size_t)n * 5;
#pragma unroll
  for (int k = 0; k < 5; ++k)
    out[(size_t)n * 320 + k * 64 + e] = __float2bfloat16(emb[(size_t)wr[k] * 64 + e]);
}

// ---------------------------------------------------------------------------
// Segment mean over contiguous groups of SEG rows: [B*SEG, C] -> [B, C]
// ---------------------------------------------------------------------------
__global__ void segmean_k(const bf16* __restrict__ x, bf16* __restrict__ out,
                          const int* __restrict__ lengths, int C, int SEG) {
  int g = blockIdx.y;
  int c = blockIdx.x * 64 + threadIdx.x;
  const bf16* p = x + (size_t)g * SEG * C + c;
  float s = 0.f;
  for (int r = 0; r < SEG; ++r) s += __bfloat162float(p[(size_t)r * C]);
  out[(size_t)g * C + c] = __float2bfloat16(s / (float)lengths[g]);
}

// ---------------------------------------------------------------------------
// bf16 MFMA GEMM: C[M,Nc] = epilogue(A[M,K] @ Bt[Nc,K]^T)
// epilogue: (+bias[col]) (+gadd[row>>segShift, col]) (leaky?) (+res[row,col]) -> bf16 or f32
// Tile 128x64, BK=64, 256 thr (4 waves 2x2, each 64x32), 16x16x32 MFMA.
// LDS: linear dest for global_load_lds, XOR-swizzled source chunks + reads (G4/rule21).
// ---------------------------------------------------------------------------
__global__ __launch_bounds__(256, 2)
void gemm_bf16_k(const bf16* __restrict__ A, const bf16* __restrict__ Bt,
                 const float* __restrict__ bias, const float* __restrict__ gadd,
                 const bf16* res, bf16* Cb, float* Cf,
                 int M, int K, int Nc, int segShift, int doLeaky)
{
  __shared__ short As[2][128 * 64];
  __shared__ short Bs[2][64 * 64];

  const int tid  = threadIdx.x;
  const int wave = tid >> 6;
  const int lane = tid & 63;
  const int wr = wave >> 1, wc = wave & 1;
  const int lrow = lane & 15, kgrp = lane >> 4;
  const int brow = blockIdx.y << 7;
  const int bcol = blockIdx.x << 6;

  const int srow   = tid >> 3;                 // 0..31 (row within 32-row chunk)
  const int schunk = (tid & 7) ^ (srow & 7);   // pre-swizzled global 16B-chunk

  f32x4 zero = {0.f, 0.f, 0.f, 0.f};
  f32x4 acc[4][2];
#pragma unroll
  for (int m = 0; m < 4; ++m)
#pragma unroll
    for (int n = 0; n < 2; ++n) acc[m][n] = zero;

  const int KT = K >> 6;

  { // prologue stage into buf 0
    const int k0 = schunk * 8;
#pragma unroll
    for (int i = 0; i < 4; ++i)
      gload_lds16(A + (size_t)(brow + i * 32 + srow) * K + k0,
                  (char*)(&As[0][0]) + i * 4096 + wave * 1024);
#pragma unroll
    for (int i = 0; i < 2; ++i)
      gload_lds16(Bt + (size_t)(bcol + i * 32 + srow) * K + k0,
                  (char*)(&Bs[0][0]) + i * 4096 + wave * 1024);
  }

  int buf = 0;
  const int swz = (lane & 7) << 4;
  for (int kt = 0; kt < KT; ++kt) {
    __syncthreads();   // drains vmcnt -> buf ready; all reads of buf^1 done
    if (kt + 1 < KT) {
      const int k0 = ((kt + 1) << 6) + schunk * 8;
#pragma unroll
      for (int i = 0; i < 4; ++i)
        gload_lds16(A + (size_t)(brow + i * 32 + srow) * K + k0,
                    (char*)(&As[buf ^ 1][0]) + i * 4096 + wave * 1024);
#pragma unroll
      for (int i = 0; i < 2; ++i)
        gload_lds16(Bt + (size_t)(bcol + i * 32 + srow) * K + k0,
                    (char*)(&Bs[buf ^ 1][0]) + i * 4096 + wave * 1024);
    }
    const char* Ab = (const char*)(&As[buf][0]);
    const char* Bb = (const char*)(&Bs[buf][0]);
#pragma unroll
    for (int kk = 0; kk < 2; ++kk) {
      const int koff = (kk * 64 + kgrp * 16) ^ swz;
      bf16x8 a[4], b[2];
#pragma unroll
      for (int m = 0; m < 4; ++m)
        a[m] = *(const bf16x8*)(Ab + (wr * 64 + m * 16 + lrow) * 128 + koff);
#pragma unroll
      for (int n = 0; n < 2; ++n)
        b[n] = *(const bf16x8*)(Bb + (wc * 32 + n * 16 + lrow) * 128 + koff);
#pragma unroll
      for (int m = 0; m < 4; ++m)
#pragma unroll
        for (int n = 0; n < 2; ++n)
          acc[m][n] = __builtin_amdgcn_mfma_f32_16x16x32_bf16(a[m], b[n], acc[m][n], 0, 0, 0);
    }
    buf ^= 1;
  }

  // epilogue: C/D layout col=lane&15, row=(lane>>4)*4+v  (m89-verified)
#pragma unroll
  for (int n = 0; n < 2; ++n) {
    const int col = bcol + wc * 32 + n * 16 + lrow;
    const float bv = bias ? bias[col] : 0.f;
#pragma unroll
    for (int m = 0; m < 4; ++m) {
      const int row0 = brow + wr * 64 + m * 16 + kgrp * 4;
#pragma unroll
      for (int v = 0; v < 4; ++v) {
        const int row = row0 + v;
        float val = acc[m][n][v] + bv;
        if (gadd) val += gadd[(size_t)(row >> segShift) * Nc + col];
        if (doLeaky) val = leakyf(val);
        if (res) val += __bfloat162float(res[(size_t)row * Nc + col]);
        if (Cb) Cb[(size_t)row * Nc + col] = __float2bfloat16(val);
        else    Cf[(size_t)row * Nc + col] = val;
      }
    }
  }
}

// ---------------------------------------------------------------------------
// Final head: y[g] = leaky(leaky(m@oW1+b1)@oW2+b2) + w*log2(len[g])
// ---------------------------------------------------------------------------
__global__ __launch_bounds__(256)
void final_head(const bf16* __restrict__ mo, const float* __restrict__ W1,
                const float* __restrict__ b1, const float* __restrict__ W2,
                const float* __restrict__ b2, const int* __restrict__ lengths,
                const float* __restrict__ wscal, float* __restrict__ out) {
  const int D = 320, H = 640;
  int g = blockIdx.x, tid = threadIdx.x;
  __shared__ float m[320];
  for (int i = tid; i < D; i += 256) m[i] = __bfloat162float(mo[(size_t)g * D + i]);
  __syncthreads();
  float partial = 0.f;
  for (int j = tid; j < H; j += 256) {
    float s = b1[j];
    for (int d = 0; d < D; ++d) s += m[d] * W1[(size_t)d * H + j];
    partial += leakyf(s) * W2[j];
  }
  __shared__ float red[256];
  red[tid] = partial; __syncthreads();
  for (int s = 128; s > 0; s >>= 1) {
    if (tid < s) red[tid] += red[tid + s];
    __syncthreads();
  }
  if (tid == 0) {
    float y = leakyf(red[0] + b2[0]);
    out[g] = y + wscal[0] * log2f((float)lengths[g]);
  }
}

// ---------------------------------------------------------------------------
extern "C" void kernel_launch(void* const* d_in, const int* in_sizes, int n_in,
                              void* d_out, int out_size, void* d_ws, size_t ws_size,
                              hipStream_t stream) {
  const int*   words   = (const int*)  d_in[0];
  const int*   lengths = (const int*)  d_in[1];
  // d_in[2] seg2all: groups are contiguous (repeat(arange(B),SEG)) -> row>>segShift
  const float* embedw  = (const float*)d_in[3];
  const float* pu_W1   = (const float*)d_in[4];
  const float* pu_b1   = (const float*)d_in[5];
  const float* pu_W2   = (const float*)d_in[6];
  const float* pu_b2   = (const float*)d_in[7];
  const float* gu_W1   = (const float*)d_in[8];
  const float* gu_b1   = (const float*)d_in[9];
  const float* gu_W2   = (const float*)d_in[10];
  const float* gu_b2   = (const float*)d_in[11];
  const float* c_W     = (const float*)d_in[12];
  const float* c_b     = (const float*)d_in[13];
  const float* o_W1    = (const float*)d_in[14];
  const float* o_b1    = (const float*)d_in[15];
  const float* o_W2    = (const float*)d_in[16];
  const float* o_b2    = (const float*)d_in[17];
  const float* wscal   = (const float*)d_in[18];

  const int B = in_sizes[1];
  const int N = in_sizes[2];
  const int SEG = N / B;
  int segShift = 0; while ((1 << segShift) < SEG) ++segShift;
  const int D = 320, H = 640, L = 3;

  size_t off = 0;
  auto alloc = [&](size_t bytes) -> void* {
    void* p = (char*)d_ws + off;
    off += (bytes + 255) & ~(size_t)255;
    return p;
  };
  bf16*  wOut = (bf16*)alloc((size_t)N * D * 2);
  bf16*  wH1  = (bf16*)alloc((size_t)N * H * 2);
  bf16*  wH   = (bf16*)alloc((size_t)N * D * 2);
  bf16*  wSeg = (bf16*)alloc((size_t)B * D * 2);
  bf16*  wT1  = (bf16*)alloc((size_t)B * H * 2);
  bf16*  wG   = (bf16*)alloc((size_t)B * D * 2);
  float* wGC  = (float*)alloc((size_t)B * D * 4);
  bf16*  tPu1 = (bf16*)alloc((size_t)L * D * H * 2);
  bf16*  tPu2 = (bf16*)alloc((size_t)L * D * H * 2);
  bf16*  tGu1 = (bf16*)alloc((size_t)L * D * H * 2);
  bf16*  tGu2 = (bf16*)alloc((size_t)L * D * H * 2);
  bf16*  tCh  = (bf16*)alloc((size_t)L * D * D * 2);
  bf16*  tCg  = (bf16*)alloc((size_t)L * D * D * 2);

  conv_w<<<dim3((D * H + 255) / 256, 5 * L), 256, 0, stream>>>(
      pu_W1, pu_W2, gu_W1, gu_W2, c_W, tPu1, tPu2, tGu1, tGu2, tCh, tCg);

  embed_k<<<(N * 64 + 255) / 256, 256, 0, stream>>>(words, embedw, wOut, N);

  for (int l = 0; l < L; ++l) {
    // h1 = leaky(out @ pu_W1 + b1)   [N,H]
    gemm_bf16_k<<<dim3(H / 64, N / 128), 256, 0, stream>>>(
        wOut, tPu1 + (size_t)l * D * H, pu_b1 + (size_t)l * H, nullptr, nullptr,
        wH1, nullptr, N, D, H, segShift, 1);
    // h = leaky(h1 @ pu_W2 + b2)     [N,D]
    gemm_bf16_k<<<dim3(D / 64, N / 128), 256, 0, stream>>>(
        wH1, tPu2 + (size_t)l * D * H, pu_b2 + (size_t)l * D, nullptr, nullptr,
        wH, nullptr, N, H, D, segShift, 1);
    // m_h = segmean(h)               [B,D]
    segmean_k<<<dim3(D / 64, B), 64, 0, stream>>>(wH, wSeg, lengths, D, SEG);
    // t1 = leaky(m_h @ gu_W1 + b1)   [B,H]
    gemm_bf16_k<<<dim3(H / 64, B / 128), 256, 0, stream>>>(
        wSeg, tGu1 + (size_t)l * D * H, gu_b1 + (size_t)l * H, nullptr, nullptr,
        wT1, nullptr, B, D, H, segShift, 1);
    // g = leaky(t1 @ gu_W2 + b2)     [B,D]
    gemm_bf16_k<<<dim3(D / 64, B / 128), 256, 0, stream>>>(
        wT1, tGu2 + (size_t)l * D * H, gu_b2 + (size_t)l * D, nullptr, nullptr,
        wG, nullptr, B, H, D, segShift, 1);
    // gc = g @ c_W[bottom]           [B,D] fp32, no act
    gemm_bf16_k<<<dim3(D / 64, B / 128), 256, 0, stream>>>(
        wG, tCg + (size_t)l * D * D, nullptr, nullptr, nullptr,
        nullptr, wGC, B, D, D, segShift, 0);
    // out = leaky(h @ c_W[top] + gc[seg] + c_b) + out   [N,D]  (in-place residual)
    gemm_bf16_k<<<dim3(D / 64, N / 128), 256, 0, stream>>>(
        wH, tCh + (size_t)l * D * D, c_b + (size_t)l * D, wGC, wOut,
        wOut, nullptr, N, D, D, segShift, 1);
  }

  segmean_k<<<dim3(D / 64, B), 64, 0, stream>>>(wOut, wSeg, lengths, D, SEG);
  final_head<<<B, 256, 0, stream>>>(wSeg, o_W1, o_b1, o_W2, o_b2, lengths, wscal,
                                    (float*)d_out);
}

// Round 2
// 665.080 us; speedup vs baseline: 1.5130x; 1.5130x over previous
//
#include <hip/hip_runtime.h>
#include <hip/hip_bf16.h>

using bf16 = __hip_bfloat16;
typedef short bf16x8 __attribute__((ext_vector_type(8)));
typedef float f32x4  __attribute__((ext_vector_type(4)));

__device__ __forceinline__ float leakyf(float x) { return x >= 0.f ? x : 0.01f * x; }

typedef const __attribute__((address_space(1))) unsigned int* gp_t;
typedef __attribute__((address_space(3))) unsigned int* lp_t;
__device__ __forceinline__ void gload16(const void* g, void* l) {
  __builtin_amdgcn_global_load_lds((gp_t)g, (lp_t)l, 16, 0, 0);
}

// ---------------------------------------------------------------------------
// Weight pre-pack: fp32 [K][Nc] row-major -> bf16 tiles in exact LDS/fragment
// consumption order: slice (colg,ks) = 64k x 320n, 40KB, laid out as
// [nt 0..19][ch 0..7][i 0..15][j 0..7]  (chunk ch = k-chunk-of-8 within 64).
// types: 0 pu_W1(K320,Nc640) 1 pu_W2(640,320) 2 gu_W1 3 gu_W2
//        4 c_W top (k<320 -> 320x320)  5 c_W bottom (k>=320)
// ---------------------------------------------------------------------------
__global__ void conv_w(const float* __restrict__ pu1, const float* __restrict__ pu2,
                       const float* __restrict__ gu1, const float* __restrict__ gu2,
                       const float* __restrict__ cw,
                       bf16* __restrict__ W0, bf16* __restrict__ W1,
                       bf16* __restrict__ W2, bf16* __restrict__ W3,
                       bf16* __restrict__ W4, bf16* __restrict__ W5) {
  int job = blockIdx.y;
  int type = job / 3, l = job % 3;
  int K, Nc, ld, koff;
  const float* s; bf16* d;
  switch (type) {
    case 0: K=320; Nc=640; ld=640; koff=0;   s=pu1 + (size_t)l*320*640; d=W0 + (size_t)l*320*640; break;
    case 1: K=640; Nc=320; ld=320; koff=0;   s=pu2 + (size_t)l*640*320; d=W1 + (size_t)l*640*320; break;
    case 2: K=320; Nc=640; ld=640; koff=0;   s=gu1 + (size_t)l*320*640; d=W2 + (size_t)l*320*640; break;
    case 3: K=640; Nc=320; ld=320; koff=0;   s=gu2 + (size_t)l*640*320; d=W3 + (size_t)l*640*320; break;
    case 4: K=320; Nc=320; ld=320; koff=0;   s=cw  + (size_t)l*640*320; d=W4 + (size_t)l*320*320; break;
    default:K=320; Nc=320; ld=320; koff=320; s=cw  + (size_t)l*640*320; d=W5 + (size_t)l*320*320; break;
  }
  const int NS = K >> 6;
  const int chunks = (K * Nc) >> 3;
  int flat = blockIdx.x * 256 + threadIdx.x;
  if (flat >= chunks) return;
  int i  = flat & 15;
  int ch = (flat >> 4) & 7;
  int nt = (flat >> 7) % 20;
  int sl = flat / 2560;            // slice id = colg*NS + ks
  int ks = sl % NS, colg = sl / NS;
  int n  = colg * 320 + nt * 16 + i;
  int kb = koff + ks * 64 + ch * 8;
  bf16 v[8];
#pragma unroll
  for (int j = 0; j < 8; ++j)
    v[j] = __float2bfloat16(s[(size_t)(kb + j) * ld + n]);
  *(bf16x8*)(d + (size_t)flat * 8) = *(bf16x8*)v;
}

// ---------------------------------------------------------------------------
// Embedding gather: out[n, w*64+e] = embed[words[n,w], e]  (bf16 row-major)
// ---------------------------------------------------------------------------
__global__ void embed_k(const int* __restrict__ words, const float* __restrict__ emb,
                        bf16* __restrict__ out, int N) {
  int i = blockIdx.x * 256 + threadIdx.x;
  if (i >= N * 64) return;
  int n = i >> 6, e = i & 63;
  const int* wr = words + (size_t)n * 5;
#pragma unroll
  for (int k = 0; k < 5; ++k)
    out[(size_t)n * 320 + k * 64 + e] = __float2bfloat16(emb[(size_t)wr[k] * 64 + e]);
}

// ---------------------------------------------------------------------------
// Unified MFMA GEMM: OUT[64 rows x 320 cols per block] = epi(A @ W)
//  - A row-major bf16, ldA == K.  - W pre-packed tiles (conv_w).
//  - grid.x = column-groups of 320 (1 or 2); grid.y = M/64.
//  - 256 thr, 4 waves, wave = 64 rows x 80 cols (4x5 tiles of 16x16x32).
//  - per k-slice 64: stage A 8KB (xor-preswizzled src, linear LDS dest) +
//    W 40KB (linear copy) via global_load_lds, 2 barriers per slice.
// flags: 1 leaky, 2 gadd (per-group add, ldOut==320), 4 residual, 8 seg-partial
// ---------------------------------------------------------------------------
__global__ __launch_bounds__(256, 3)
void mm_k(const bf16* __restrict__ A, const bf16* __restrict__ Wt,
          const float* __restrict__ bias, const bf16* __restrict__ gadd,
          const bf16* __restrict__ res, bf16* __restrict__ out,
          float* __restrict__ part,
          int K, int ldOut, int flags)
{
  __shared__ short As[4096];     // 8 KB : A slice [64 rows][64 k] (xor-swizzled)
  __shared__ short Ws[20480];    // 40 KB: W slice [20 nt][8 ch][16 i][8 j]

  const int NS   = K >> 6;
  const int tid  = threadIdx.x;
  const int lane = tid & 63;
  const int wv   = tid >> 6;          // wave 0..3 -> column group of 80
  const int i16  = lane & 15;
  const int kg   = lane >> 4;
  const int rb   = blockIdx.y << 6;
  const int colBase = blockIdx.x * 320;

  f32x4 zero = {0.f, 0.f, 0.f, 0.f};
  f32x4 acc[4][5];
#pragma unroll
  for (int m = 0; m < 4; ++m)
#pragma unroll
    for (int n = 0; n < 5; ++n) acc[m][n] = zero;

  const bf16* wbase = Wt + (size_t)blockIdx.x * NS * 20480;

  for (int ks = 0; ks < NS; ++ks) {
    __syncthreads();                       // LDS reuse safe (reads of prev slice done)
    // ---- stage A slice: 512 chunks of 16B, xor-preswizzled source ----
#pragma unroll
    for (int t = 0; t < 2; ++t) {
      int d0 = (t * 4 + wv) * 64;
      int d  = d0 + lane;
      int row = d >> 3, c = d & 7;
      gload16(A + (size_t)(rb + row) * K + ks * 64 + ((c ^ (row & 7)) << 3),
              (char*)As + d0 * 16);
    }
    // ---- stage W slice: 2560 chunks, pure linear copy ----
    const bf16* wsrc = wbase + (size_t)ks * 20480;
#pragma unroll
    for (int t = 0; t < 10; ++t) {
      int d0 = (t * 4 + wv) * 64;
      gload16(wsrc + (size_t)(d0 + lane) * 8, (char*)Ws + d0 * 16);
    }
    __syncthreads();                       // drains vmcnt -> slice ready
    // ---- compute: 2 x k32 steps, 20 mfma each ----
#pragma unroll
    for (int kk = 0; kk < 2; ++kk) {
      bf16x8 a[4], b[5];
#pragma unroll
      for (int m = 0; m < 4; ++m) {
        int row = m * 16 + i16;
        a[m] = *(const bf16x8*)((const char*)As + row * 128 +
                                (((kk * 4 + kg) ^ (row & 7)) << 4));
      }
#pragma unroll
      for (int n = 0; n < 5; ++n)
        b[n] = *(const bf16x8*)((const char*)Ws +
                                ((wv * 5 + n) * 8 + kk * 4 + kg) * 256 + i16 * 16);
#pragma unroll
      for (int m = 0; m < 4; ++m)
#pragma unroll
        for (int n = 0; n < 5; ++n)
          acc[m][n] = __builtin_amdgcn_mfma_f32_16x16x32_bf16(a[m], b[n], acc[m][n], 0, 0, 0);
    }
  }

  // ---- epilogue ----
  const bool doLeaky = flags & 1, useG = flags & 2, useR = flags & 4, doSeg = flags & 8;
  const bf16* gptr = useG ? gadd + (size_t)(blockIdx.y >> 1) * 320 : nullptr;
#pragma unroll
  for (int n = 0; n < 5; ++n) {
    const int col = colBase + wv * 80 + n * 16 + i16;
    const float bv = bias ? bias[col] : 0.f;
    float ga = useG ? __bfloat162float(gptr[col]) : 0.f;
    float csum = 0.f;
#pragma unroll
    for (int m = 0; m < 4; ++m) {
#pragma unroll
      for (int v = 0; v < 4; ++v) {
        const int row = rb + m * 16 + kg * 4 + v;
        float val = acc[m][n][v] + bv + ga;
        if (doLeaky) val = leakyf(val);
        if (useR) val += __bfloat162float(res[(size_t)row * ldOut + col]);
        out[(size_t)row * ldOut + col] = __float2bfloat16(val);
        csum += val;
      }
    }
    if (doSeg) {
      csum += __shfl_xor(csum, 16, 64);
      csum += __shfl_xor(csum, 32, 64);
      if (lane < 16) part[(size_t)blockIdx.y * 320 + col] = csum;
    }
  }
}

// ---------------------------------------------------------------------------
// Finish segment mean from per-64-row partials: seg[g][c] = (p[2g]+p[2g+1])/len
// ---------------------------------------------------------------------------
__global__ void gseg_k(const float* __restrict__ part, const int* __restrict__ len,
                       bf16* __restrict__ seg, int B) {
  int idx = blockIdx.x * 256 + threadIdx.x;
  if (idx >= B * 320) return;
  int g = idx / 320, c = idx - g * 320;
  float s = part[(size_t)(2 * g) * 320 + c] + part[(size_t)(2 * g + 1) * 320 + c];
  seg[idx] = __float2bfloat16(s / (float)len[g]);
}

// ---------------------------------------------------------------------------
// Final head: y[g] = leaky(leaky(m@oW1+b1)@oW2+b2) + w*log2(len[g])
// ---------------------------------------------------------------------------
__global__ __launch_bounds__(256)
void final_head(const bf16* __restrict__ mo, const float* __restrict__ W1,
                const float* __restrict__ b1, const float* __restrict__ W2,
                const float* __restrict__ b2, const int* __restrict__ lengths,
                const float* __restrict__ wscal, float* __restrict__ out) {
  const int D = 320, H = 640;
  int g = blockIdx.x, tid = threadIdx.x;
  __shared__ float m[320];
  for (int i = tid; i < D; i += 256) m[i] = __bfloat162float(mo[(size_t)g * D + i]);
  __syncthreads();
  float partial = 0.f;
  for (int j = tid; j < H; j += 256) {
    float s = b1[j];
    for (int d = 0; d < D; ++d) s += m[d] * W1[(size_t)d * H + j];
    partial += leakyf(s) * W2[j];
  }
  __shared__ float red[256];
  red[tid] = partial; __syncthreads();
  for (int s = 128; s > 0; s >>= 1) {
    if (tid < s) red[tid] += red[tid + s];
    __syncthreads();
  }
  if (tid == 0) {
    float y = leakyf(red[0] + b2[0]);
    out[g] = y + wscal[0] * log2f((float)lengths[g]);
  }
}

// ---------------------------------------------------------------------------
extern "C" void kernel_launch(void* const* d_in, const int* in_sizes, int n_in,
                              void* d_out, int out_size, void* d_ws, size_t ws_size,
                              hipStream_t stream) {
  const int*   words   = (const int*)  d_in[0];
  const int*   lengths = (const int*)  d_in[1];
  // d_in[2] seg2all: contiguous groups (repeat(arange(B),SEG)) -> group = row/SEG
  const float* embedw  = (const float*)d_in[3];
  const float* pu_W1   = (const float*)d_in[4];
  const float* pu_b1   = (const float*)d_in[5];
  const float* pu_W2   = (const float*)d_in[6];
  const float* pu_b2   = (const float*)d_in[7];
  const float* gu_W1   = (const float*)d_in[8];
  const float* gu_b1   = (const float*)d_in[9];
  const float* gu_W2   = (const float*)d_in[10];
  const float* gu_b2   = (const float*)d_in[11];
  const float* c_W     = (const float*)d_in[12];
  const float* c_b     = (const float*)d_in[13];
  const float* o_W1    = (const float*)d_in[14];
  const float* o_b1    = (const float*)d_in[15];
  const float* o_W2    = (const float*)d_in[16];
  const float* o_b2    = (const float*)d_in[17];
  const float* wscal   = (const float*)d_in[18];

  const int B = in_sizes[1];
  const int N = in_sizes[2];
  const int L = 3;

  size_t off = 0;
  auto alloc = [&](size_t bytes) -> void* {
    void* p = (char*)d_ws + off;
    off += (bytes + 255) & ~(size_t)255;
    return p;
  };
  bf16*  wOut  = (bf16*) alloc((size_t)N * 320 * 2);
  bf16*  wH1   = (bf16*) alloc((size_t)N * 640 * 2);
  bf16*  wH    = (bf16*) alloc((size_t)N * 320 * 2);
  bf16*  wSeg  = (bf16*) alloc((size_t)B * 320 * 2);
  bf16*  wT1   = (bf16*) alloc((size_t)B * 640 * 2);
  bf16*  wG    = (bf16*) alloc((size_t)B * 320 * 2);
  bf16*  wGC   = (bf16*) alloc((size_t)B * 320 * 2);
  float* wPart = (float*)alloc((size_t)(N / 64) * 320 * 4);
  bf16*  W0 = (bf16*)alloc((size_t)L * 320 * 640 * 2);
  bf16*  W1 = (bf16*)alloc((size_t)L * 640 * 320 * 2);
  bf16*  W2 = (bf16*)alloc((size_t)L * 320 * 640 * 2);
  bf16*  W3 = (bf16*)alloc((size_t)L * 640 * 320 * 2);
  bf16*  W4 = (bf16*)alloc((size_t)L * 320 * 320 * 2);
  bf16*  W5 = (bf16*)alloc((size_t)L * 320 * 320 * 2);

  conv_w<<<dim3(100, 18), 256, 0, stream>>>(pu_W1, pu_W2, gu_W1, gu_W2, c_W,
                                            W0, W1, W2, W3, W4, W5);
  embed_k<<<(N * 64 + 255) / 256, 256, 0, stream>>>(words, embedw, wOut, N);

  for (int l = 0; l < L; ++l) {
    // h1 = leaky(out @ pu_W1 + b1)   [N,640]
    mm_k<<<dim3(2, N / 64), 256, 0, stream>>>(
        wOut, W0 + (size_t)l * 320 * 640, pu_b1 + (size_t)l * 640,
        nullptr, nullptr, wH1, nullptr, 320, 640, 1);
    // h = leaky(h1 @ pu_W2 + b2)     [N,320]  + segment partial sums
    mm_k<<<dim3(1, N / 64), 256, 0, stream>>>(
        wH1, W1 + (size_t)l * 640 * 320, pu_b2 + (size_t)l * 320,
        nullptr, nullptr, wH, wPart, 640, 320, 1 | 8);
    // m = segmean(h)                 [B,320]
    gseg_k<<<(B * 320 + 255) / 256, 256, 0, stream>>>(wPart, lengths, wSeg, B);
    // t1 = leaky(m @ gu_W1 + b1)     [B,640]
    mm_k<<<dim3(2, B / 64), 256, 0, stream>>>(
        wSeg, W2 + (size_t)l * 320 * 640, gu_b1 + (size_t)l * 640,
        nullptr, nullptr, wT1, nullptr, 320, 640, 1);
    // g = leaky(t1 @ gu_W2 + b2)     [B,320]
    mm_k<<<dim3(1, B / 64), 256, 0, stream>>>(
        wT1, W3 + (size_t)l * 640 * 320, gu_b2 + (size_t)l * 320,
        nullptr, nullptr, wG, nullptr, 640, 320, 1);
    // gc = g @ c_W[320:]             [B,320]
    mm_k<<<dim3(1, B / 64), 256, 0, stream>>>(
        wG, W5 + (size_t)l * 320 * 320, nullptr,
        nullptr, nullptr, wGC, nullptr, 320, 320, 0);
    // out = leaky(h @ c_W[:320] + gc[group] + c_b) + out   (in-place residual)
    mm_k<<<dim3(1, N / 64), 256, 0, stream>>>(
        wH, W4 + (size_t)l * 320 * 320, c_b + (size_t)l * 320,
        wGC, wOut, wOut, wPart, 320, 320, 1 | 2 | 4 | ((l == 2) ? 8 : 0));
  }

  gseg_k<<<(B * 320 + 255) / 256, 256, 0, stream>>>(wPart, lengths, wSeg, B);
  final_head<<<B, 256, 0, stream>>>(wSeg, o_W1, o_b1, o_W2, o_b2, lengths, wscal,
                                    (float*)d_out);
}